// Round 4
// baseline (139.664 us; speedup 1.0000x reference)
//
#include <hip/hip_runtime.h>
#include <cmath>

#define NBATCH 8
#define NGT    64
#define NPR    32768
#define NC     80

#define CHUNKS 16
#define CHUNK  (NPR / CHUNKS)   // 2048 anchors per chunk
#define GTPB   8                // gt boxes per block (phase 1)
#define APT    2                // anchors per thread (phase 2)
#define APB    (256 * APT)      // anchors per block  (phase 2) = 512

typedef float v4f __attribute__((ext_vector_type(4)));

// -------- Phase 1: per-(b,g) partial argmax over one anchor chunk. --------
__global__ __launch_bounds__(256) void k_bestp_part(const float* __restrict__ gt,
                                                    const float* __restrict__ pr,
                                                    float* __restrict__ pval,
                                                    int* __restrict__ pidx) {
#pragma clang fp contract(off)
    const int chunk = blockIdx.x;    // 0..15
    const int gg    = blockIdx.y;    // 0..63  (bg group of 8)
    const int tid   = threadIdx.x;

    __shared__ float sy1[GTPB], sx1[GTPB], sy2[GTPB], sx2[GTPB], sga[GTPB];
    __shared__ int   sv[GTPB];
    if (tid < GTPB) {
        const float* g6 = gt + ((size_t)gg * GTPB + tid) * 6;
        float cx = g6[0], cy = g6[1], w = g6[2], h = g6[3];
        sy1[tid] = cy - h * 0.5f;
        sx1[tid] = cx - w * 0.5f;
        sy2[tid] = cy + h * 0.5f;
        sx2[tid] = cx + w * 0.5f;
        sga[tid] = w * h;
        sv[tid]  = (cx != -1.0f) ? 1 : 0;
    }
    __syncthreads();

    float gy1[GTPB], gx1[GTPB], gy2[GTPB], gx2[GTPB], ga[GTPB];
    int   gv[GTPB];
    #pragma unroll
    for (int j = 0; j < GTPB; ++j) {
        gy1[j] = sy1[j]; gx1[j] = sx1[j]; gy2[j] = sy2[j]; gx2[j] = sx2[j];
        ga[j] = sga[j]; gv[j] = sv[j];
    }

    float best[GTPB]; int bi[GTPB];
    #pragma unroll
    for (int j = 0; j < GTPB; ++j) { best[j] = -1.0f; bi[j] = 0; }

    const int base = chunk * CHUNK;
    #pragma unroll 4
    for (int k = 0; k < CHUNK / 256; ++k) {          // 8 iterations
        int p = base + k * 256 + tid;                // ascending p per thread
        float4 pv = ((const float4*)pr)[p];
        float py1 = pv.y - pv.w * 0.5f;
        float px1 = pv.x - pv.z * 0.5f;
        float py2 = pv.y + pv.w * 0.5f;
        float px2 = pv.x + pv.z * 0.5f;
        float pa  = pv.z * pv.w;
        #pragma unroll
        for (int j = 0; j < GTPB; ++j) {
            float ih = fmaxf(0.0f, fminf(gy2[j], py2) - fmaxf(gy1[j], py1));
            float iw = fmaxf(0.0f, fminf(gx2[j], px2) - fmaxf(gx1[j], px1));
            float inter = iw * ih;
            float uni   = ga[j] + pa - inter;
            float iou   = inter / (uni + 1e-5f);
            iou = gv[j] ? iou : 0.0f;
            if (iou > best[j]) { best[j] = iou; bi[j] = p; }
        }
    }

    // 64-lane shuffle argmax per gt (lower idx wins ties)
    #pragma unroll
    for (int j = 0; j < GTPB; ++j) {
        #pragma unroll
        for (int off = 32; off > 0; off >>= 1) {
            float ov = __shfl_down(best[j], off);
            int   oi = __shfl_down(bi[j], off);
            if (ov > best[j] || (ov == best[j] && oi < bi[j])) {
                best[j] = ov; bi[j] = oi;
            }
        }
    }

    __shared__ float rv[4][GTPB];
    __shared__ int   rix[4][GTPB];
    const int wave = tid >> 6;
    if ((tid & 63) == 0) {
        #pragma unroll
        for (int j = 0; j < GTPB; ++j) { rv[wave][j] = best[j]; rix[wave][j] = bi[j]; }
    }
    __syncthreads();
    if (tid < GTPB) {
        float v = rv[0][tid]; int i = rix[0][tid];
        #pragma unroll
        for (int w = 1; w < 4; ++w) {
            float v2 = rv[w][tid]; int i2 = rix[w][tid];
            if (v2 > v || (v2 == v && i2 < i)) { v = v2; i = i2; }
        }
        int bg = gg * GTPB + tid;
        pval[bg * CHUNKS + chunk] = v;
        pidx[bg * CHUNKS + chunk] = i;
    }
}

// -------- Phase 1b: combine chunk partials + build per-(b,g) record.
// prep[bg] = { y1,x1,y2,x2 | ga,cx,cy,lab | lw,lh,bitcast(bp'),0 }
// Invalid boxes: y1=y2=3e38 -> ih==+0 -> inter==+0 -> iou==+0 exactly. ----
__global__ __launch_bounds__(256) void k_finish(const float* __restrict__ gt,
                                                const float* __restrict__ pval,
                                                const int* __restrict__ pidx,
                                                float* __restrict__ prep) {
#pragma clang fp contract(off)
    const int bg = blockIdx.x * 256 + threadIdx.x;
    if (bg >= NBATCH * NGT) return;
    const float* g6 = gt + (size_t)bg * 6;
    float cx = g6[0], cy = g6[1], w = g6[2], h = g6[3], lab = g6[4], conf = g6[5];
    bool valid = (cx != -1.0f);
    float y1 = cy - h * 0.5f;
    float x1 = cx - w * 0.5f;
    float y2 = cy + h * 0.5f;
    float x2 = cx + w * 0.5f;
    if (!valid) { y1 = 3e38f; y2 = 3e38f; }
    float ga = w * h;
    float lw = (w > 0.0f) ? logf(fmaxf(w, 1e-20f)) : 0.0f;
    float lh = (h > 0.0f) ? logf(fmaxf(h, 1e-20f)) : 0.0f;

    float v = pval[bg * CHUNKS + 0]; int i = pidx[bg * CHUNKS + 0];
    #pragma unroll
    for (int c = 1; c < CHUNKS; ++c) {
        float v2 = pval[bg * CHUNKS + c]; int i2 = pidx[bg * CHUNKS + c];
        if (v2 > v || (v2 == v && i2 < i)) { v = v2; i = i2; }
    }
    int bp = (conf > 0.0f) ? i : -1;   // 'best' requires gt_conf > 0

    float4* q = (float4*)prep + (size_t)bg * 3;
    q[0] = make_float4(y1, x1, y2, x2);
    q[1] = make_float4(ga, cx, cy, lab);
    q[2] = make_float4(lw, lh, __int_as_float(bp), 0.0f);
}

// -------- Phase 2: per-(b,p) assignment, 2 anchors/thread.
// g-loop reads 3 x ds_read_b128 per g, shared by both anchors. --------
__global__ __launch_bounds__(256) void k_assign(const float* __restrict__ pr,
                                                const float* __restrict__ prep,
                                                float* __restrict__ out_cls,
                                                float* __restrict__ out_loc,
                                                float* __restrict__ out_msk) {
#pragma clang fp contract(off)
    const int b   = blockIdx.y;
    const int tid = threadIdx.x;
    const int p0  = blockIdx.x * APB + tid;      // anchors p0, p0+256

    __shared__ float4 sq[NGT * 3];               // 3 KB broadcast table
    __shared__ int    s_cls[APB];
    if (tid < NGT * 3) sq[tid] = ((const float4*)prep)[(size_t)b * NGT * 3 + tid];
    __syncthreads();

    float px[APT], py[APT], pw[APT], ph[APT];
    float py1[APT], px1[APT], py2[APT], px2[APT], pa[APT];
    #pragma unroll
    for (int a = 0; a < APT; ++a) {
        float4 pv = ((const float4*)pr)[p0 + a * 256];
        px[a] = pv.x; py[a] = pv.y; pw[a] = pv.z; ph[a] = pv.w;
        py1[a] = pv.y - pv.w * 0.5f;
        px1[a] = pv.x - pv.z * 0.5f;
        py2[a] = pv.y + pv.w * 0.5f;
        px2[a] = pv.x + pv.z * 0.5f;
        pa[a]  = pv.z * pv.w;
    }

    int  g_th[APT], g_bs[APT];
    bool ign[APT];
    float W[APT], Scx[APT], Scy[APT], Slw[APT], Slh[APT];
    #pragma unroll
    for (int a = 0; a < APT; ++a) {
        g_th[a] = -1; g_bs[a] = -1; ign[a] = false;
        W[a] = 0.0f; Scx[a] = 0.0f; Scy[a] = 0.0f; Slw[a] = 0.0f; Slh[a] = 0.0f;
    }

    #pragma unroll 4
    for (int g = 0; g < NGT; ++g) {
        float4 q0 = sq[3 * g + 0];   // y1 x1 y2 x2
        float4 q1 = sq[3 * g + 1];   // ga cx cy lab
        float4 q2 = sq[3 * g + 2];   // lw lh bp' -
        int bp = __float_as_int(q2.z);
        #pragma unroll
        for (int a = 0; a < APT; ++a) {
            float ih = fmaxf(0.0f, fminf(q0.z, py2[a]) - fmaxf(q0.x, py1[a]));
            float iw = fmaxf(0.0f, fminf(q0.w, px2[a]) - fmaxf(q0.y, px1[a]));
            float inter = iw * ih;
            float uni   = q1.x + pa[a] - inter;
            float iou   = inter / (uni + 1e-5f);
            bool th = (iou >= 0.5f);
            bool bs = (bp == p0 + a * 256);
            if (th) g_th[a] = g;
            if (bs) g_bs[a] = g;
            ign[a] = ign[a] || (iou < 0.5f && iou >= 0.4f);
            float wg = (float)th + (float)bs;
            W[a]   += wg;
            Scx[a] += wg * q1.y;
            Scy[a] += wg * q1.z;
            Slw[a] += wg * q2.x;
            Slh[a] += wg * q2.y;
        }
    }

    #pragma unroll
    for (int a = 0; a < APT; ++a) {
        const int  win     = (g_bs[a] >= 0) ? g_bs[a] : g_th[a];
        const bool matched = (win >= 0);
        float labf = sq[3 * (matched ? win : 0) + 1].w;   // LDS gather
        const int cls = matched ? (int)labf : NC;
        float msk = matched ? 0.0f : 1.0f;
        if (ign[a]) msk = -1.0f;

        const float hcx = (Scx[a] - W[a] * px[a]) / pw[a];
        const float hcy = (Scy[a] - W[a] * py[a]) / ph[a];
        const float hw  = Slw[a] - W[a] * logf(pw[a]);
        const float hh  = Slh[a] - W[a] * logf(ph[a]);

        const size_t bp_i = (size_t)b * NPR + p0 + a * 256;
        ((float4*)out_loc)[bp_i] = make_float4(hcx, hcy, hw, hh);
        out_msk[bp_i] = msk;
        s_cls[tid + a * 256] = cls;
    }
    __syncthreads();

    // Cooperative coalesced one-hot tile: 512 anchors x 80 classes (160 KB),
    // nontemporal (write-once stream, no reuse).
    const size_t base4 = ((size_t)b * NPR + (size_t)blockIdx.x * APB) * NC / 4;
    v4f* oc4 = (v4f*)out_cls;
    #pragma unroll
    for (int k = 0; k < (APB * NC / 4) / 256; ++k) {   // 40 iterations
        int idx = tid + k * 256;
        int e0  = idx * 4;
        int pl  = e0 / NC;
        int c0  = e0 - pl * NC;
        int cl  = s_cls[pl];
        v4f v;
        v.x = (c0     == cl) ? 1.0f : 0.0f;
        v.y = (c0 + 1 == cl) ? 1.0f : 0.0f;
        v.z = (c0 + 2 == cl) ? 1.0f : 0.0f;
        v.w = (c0 + 3 == cl) ? 1.0f : 0.0f;
        __builtin_nontemporal_store(v, &oc4[base4 + idx]);
    }
}

extern "C" void kernel_launch(void* const* d_in, const int* in_sizes, int n_in,
                              void* d_out, int out_size, void* d_ws, size_t ws_size,
                              hipStream_t stream) {
    const float* gt = (const float*)d_in[0];
    const float* pr = (const float*)d_in[1];   // reference uses pr_boxes[0] only

    float* pval = (float*)d_ws;                              // 512*16 floats
    int*   pidx = (int*)((char*)d_ws + 32 * 1024);           // 512*16 ints
    float* prep = (float*)((char*)d_ws + 64 * 1024);         // 512*12 floats

    float* out_cls = (float*)d_out;                          // B*P*80
    float* out_loc = out_cls + (size_t)NBATCH * NPR * NC;    // B*P*4
    float* out_msk = out_loc + (size_t)NBATCH * NPR * 4;     // B*P

    dim3 g1(CHUNKS, NBATCH * NGT / GTPB);    // 16 x 64 = 1024 blocks
    k_bestp_part<<<g1, 256, 0, stream>>>(gt, pr, pval, pidx);

    k_finish<<<(NBATCH * NGT + 255) / 256, 256, 0, stream>>>(gt, pval, pidx, prep);

    dim3 g2(NPR / APB, NBATCH);              // 64 x 8 = 512 blocks
    k_assign<<<g2, 256, 0, stream>>>(pr, prep, out_cls, out_loc, out_msk);
}

// Round 5
// 131.651 us; speedup vs baseline: 1.0609x; 1.0609x over previous
//
#include <hip/hip_runtime.h>
#include <cmath>

#define NBATCH 8
#define NGT    64
#define NPR    32768
#define NC     80

#define CHUNKS 16
#define CHUNK  (NPR / CHUNKS)   // 2048 anchors per chunk
#define GTPB   8                // gt boxes per block (phase 1)
#define APT    2                // anchors per thread (phase 2)
#define APB    (256 * APT)      // anchors per block  (phase 2) = 512

// -------- Phase 1: per-(b,g) partial argmax over one anchor chunk.
// numpy tie-break (first index of the max) preserved at every level. --------
__global__ __launch_bounds__(256) void k_bestp_part(const float* __restrict__ gt,
                                                    const float* __restrict__ pr,
                                                    float* __restrict__ pval,
                                                    int* __restrict__ pidx) {
#pragma clang fp contract(off)
    const int chunk = blockIdx.x;    // 0..15
    const int gg    = blockIdx.y;    // 0..63  (bg group of 8)
    const int tid   = threadIdx.x;

    __shared__ float sy1[GTPB], sx1[GTPB], sy2[GTPB], sx2[GTPB], sga[GTPB];
    __shared__ int   sv[GTPB];
    if (tid < GTPB) {
        const float* g6 = gt + ((size_t)gg * GTPB + tid) * 6;
        float cx = g6[0], cy = g6[1], w = g6[2], h = g6[3];
        sy1[tid] = cy - h * 0.5f;
        sx1[tid] = cx - w * 0.5f;
        sy2[tid] = cy + h * 0.5f;
        sx2[tid] = cx + w * 0.5f;
        sga[tid] = w * h;
        sv[tid]  = (cx != -1.0f) ? 1 : 0;
    }
    __syncthreads();

    float gy1[GTPB], gx1[GTPB], gy2[GTPB], gx2[GTPB], ga[GTPB];
    int   gv[GTPB];
    #pragma unroll
    for (int j = 0; j < GTPB; ++j) {
        gy1[j] = sy1[j]; gx1[j] = sx1[j]; gy2[j] = sy2[j]; gx2[j] = sx2[j];
        ga[j] = sga[j]; gv[j] = sv[j];
    }

    float best[GTPB]; int bi[GTPB];
    #pragma unroll
    for (int j = 0; j < GTPB; ++j) { best[j] = -1.0f; bi[j] = 0; }

    const int base = chunk * CHUNK;
    #pragma unroll 4
    for (int k = 0; k < CHUNK / 256; ++k) {          // 8 iterations
        int p = base + k * 256 + tid;                // ascending p per thread
        float4 pv = ((const float4*)pr)[p];
        float py1 = pv.y - pv.w * 0.5f;
        float px1 = pv.x - pv.z * 0.5f;
        float py2 = pv.y + pv.w * 0.5f;
        float px2 = pv.x + pv.z * 0.5f;
        float pa  = pv.z * pv.w;
        #pragma unroll
        for (int j = 0; j < GTPB; ++j) {
            float ih = fmaxf(0.0f, fminf(gy2[j], py2) - fmaxf(gy1[j], py1));
            float iw = fmaxf(0.0f, fminf(gx2[j], px2) - fmaxf(gx1[j], px1));
            float inter = iw * ih;
            float uni   = ga[j] + pa - inter;
            float iou   = inter / (uni + 1e-5f);
            iou = gv[j] ? iou : 0.0f;
            if (iou > best[j]) { best[j] = iou; bi[j] = p; }
        }
    }

    // 64-lane shuffle argmax per gt (lower idx wins ties)
    #pragma unroll
    for (int j = 0; j < GTPB; ++j) {
        #pragma unroll
        for (int off = 32; off > 0; off >>= 1) {
            float ov = __shfl_down(best[j], off);
            int   oi = __shfl_down(bi[j], off);
            if (ov > best[j] || (ov == best[j] && oi < bi[j])) {
                best[j] = ov; bi[j] = oi;
            }
        }
    }

    __shared__ float rv[4][GTPB];
    __shared__ int   rix[4][GTPB];
    const int wave = tid >> 6;
    if ((tid & 63) == 0) {
        #pragma unroll
        for (int j = 0; j < GTPB; ++j) { rv[wave][j] = best[j]; rix[wave][j] = bi[j]; }
    }
    __syncthreads();
    if (tid < GTPB) {
        float v = rv[0][tid]; int i = rix[0][tid];
        #pragma unroll
        for (int w = 1; w < 4; ++w) {
            float v2 = rv[w][tid]; int i2 = rix[w][tid];
            if (v2 > v || (v2 == v && i2 < i)) { v = v2; i = i2; }
        }
        int bg = gg * GTPB + tid;
        pval[bg * CHUNKS + chunk] = v;
        pidx[bg * CHUNKS + chunk] = i;
    }
}

// -------- Phase 2: per-(b,p) assignment, 2 anchors/thread.
// Preamble folds the chunk-partial combine + per-g record build into an LDS
// float4 table (redundantly per block — 8 KB of L2-resident reads).
// Invalid boxes: y1=y2=3e38 -> ih==+0 -> inter==+0 -> iou==+0 exactly,
// matching the reference's iou*valid with no per-g select. --------
__global__ __launch_bounds__(256) void k_assign(const float* __restrict__ gt,
                                                const float* __restrict__ pr,
                                                const float* __restrict__ pval,
                                                const int* __restrict__ pidx,
                                                float* __restrict__ out_cls,
                                                float* __restrict__ out_loc,
                                                float* __restrict__ out_msk) {
#pragma clang fp contract(off)
    const int b   = blockIdx.y;
    const int tid = threadIdx.x;
    const int p0  = blockIdx.x * APB + tid;      // anchors p0, p0+256

    __shared__ float4 sq[NGT * 3];               // 3 KB broadcast table
    __shared__ int    s_cls[APB];

    if (tid < NGT) {
        const int bg = b * NGT + tid;
        const float* g6 = gt + (size_t)bg * 6;
        float cx = g6[0], cy = g6[1], w = g6[2], h = g6[3], lab = g6[4], conf = g6[5];
        bool valid = (cx != -1.0f);
        float y1 = cy - h * 0.5f;
        float x1 = cx - w * 0.5f;
        float y2 = cy + h * 0.5f;
        float x2 = cx + w * 0.5f;
        if (!valid) { y1 = 3e38f; y2 = 3e38f; }
        float ga = w * h;
        float lw = (w > 0.0f) ? logf(fmaxf(w, 1e-20f)) : 0.0f;
        float lh = (h > 0.0f) ? logf(fmaxf(h, 1e-20f)) : 0.0f;

        // combine chunk partials (ascending chunk => ascending p; low idx wins)
        float v = pval[bg * CHUNKS + 0]; int i = pidx[bg * CHUNKS + 0];
        #pragma unroll
        for (int c = 1; c < CHUNKS; ++c) {
            float v2 = pval[bg * CHUNKS + c]; int i2 = pidx[bg * CHUNKS + c];
            if (v2 > v || (v2 == v && i2 < i)) { v = v2; i = i2; }
        }
        int bp = (conf > 0.0f) ? i : -1;   // 'best' requires gt_conf > 0

        sq[3 * tid + 0] = make_float4(y1, x1, y2, x2);
        sq[3 * tid + 1] = make_float4(ga, cx, cy, lab);
        sq[3 * tid + 2] = make_float4(lw, lh, __int_as_float(bp), 0.0f);
    }
    __syncthreads();

    float px[APT], py[APT], pw[APT], ph[APT];
    float py1[APT], px1[APT], py2[APT], px2[APT], pa[APT];
    #pragma unroll
    for (int a = 0; a < APT; ++a) {
        float4 pv = ((const float4*)pr)[p0 + a * 256];
        px[a] = pv.x; py[a] = pv.y; pw[a] = pv.z; ph[a] = pv.w;
        py1[a] = pv.y - pv.w * 0.5f;
        px1[a] = pv.x - pv.z * 0.5f;
        py2[a] = pv.y + pv.w * 0.5f;
        px2[a] = pv.x + pv.z * 0.5f;
        pa[a]  = pv.z * pv.w;
    }

    int  g_th[APT], g_bs[APT];
    bool ign[APT];
    float W[APT], Scx[APT], Scy[APT], Slw[APT], Slh[APT];
    #pragma unroll
    for (int a = 0; a < APT; ++a) {
        g_th[a] = -1; g_bs[a] = -1; ign[a] = false;
        W[a] = 0.0f; Scx[a] = 0.0f; Scy[a] = 0.0f; Slw[a] = 0.0f; Slh[a] = 0.0f;
    }

    #pragma unroll 4
    for (int g = 0; g < NGT; ++g) {
        float4 q0 = sq[3 * g + 0];   // y1 x1 y2 x2
        float4 q1 = sq[3 * g + 1];   // ga cx cy lab
        float4 q2 = sq[3 * g + 2];   // lw lh bp' -
        int bp = __float_as_int(q2.z);
        #pragma unroll
        for (int a = 0; a < APT; ++a) {
            float ih = fmaxf(0.0f, fminf(q0.z, py2[a]) - fmaxf(q0.x, py1[a]));
            float iw = fmaxf(0.0f, fminf(q0.w, px2[a]) - fmaxf(q0.y, px1[a]));
            float inter = iw * ih;
            float uni   = q1.x + pa[a] - inter;
            float iou   = inter / (uni + 1e-5f);
            bool th = (iou >= 0.5f);
            bool bs = (bp == p0 + a * 256);
            if (th) g_th[a] = g;
            if (bs) g_bs[a] = g;
            ign[a] = ign[a] || (iou < 0.5f && iou >= 0.4f);
            float wg = (float)th + (float)bs;
            W[a]   += wg;
            Scx[a] += wg * q1.y;
            Scy[a] += wg * q1.z;
            Slw[a] += wg * q2.x;
            Slh[a] += wg * q2.y;
        }
    }

    #pragma unroll
    for (int a = 0; a < APT; ++a) {
        const int  win     = (g_bs[a] >= 0) ? g_bs[a] : g_th[a];
        const bool matched = (win >= 0);
        float labf = sq[3 * (matched ? win : 0) + 1].w;   // LDS gather
        const int cls = matched ? (int)labf : NC;
        float msk = matched ? 0.0f : 1.0f;
        if (ign[a]) msk = -1.0f;

        const float hcx = (Scx[a] - W[a] * px[a]) / pw[a];
        const float hcy = (Scy[a] - W[a] * py[a]) / ph[a];
        const float hw  = Slw[a] - W[a] * logf(pw[a]);
        const float hh  = Slh[a] - W[a] * logf(ph[a]);

        const size_t bp_i = (size_t)b * NPR + p0 + a * 256;
        ((float4*)out_loc)[bp_i] = make_float4(hcx, hcy, hw, hh);
        out_msk[bp_i] = msk;
        s_cls[tid + a * 256] = cls;
    }
    __syncthreads();

    // Cooperative coalesced one-hot tile: 512 anchors x 80 classes (160 KB).
    const size_t base4 = ((size_t)b * NPR + (size_t)blockIdx.x * APB) * NC / 4;
    float4* oc4 = (float4*)out_cls;
    #pragma unroll
    for (int k = 0; k < (APB * NC / 4) / 256; ++k) {   // 40 iterations
        int idx = tid + k * 256;
        int e0  = idx * 4;
        int pl  = e0 / NC;
        int c0  = e0 - pl * NC;
        int cl  = s_cls[pl];
        float4 v;
        v.x = (c0     == cl) ? 1.0f : 0.0f;
        v.y = (c0 + 1 == cl) ? 1.0f : 0.0f;
        v.z = (c0 + 2 == cl) ? 1.0f : 0.0f;
        v.w = (c0 + 3 == cl) ? 1.0f : 0.0f;
        oc4[base4 + idx] = v;
    }
}

extern "C" void kernel_launch(void* const* d_in, const int* in_sizes, int n_in,
                              void* d_out, int out_size, void* d_ws, size_t ws_size,
                              hipStream_t stream) {
    const float* gt = (const float*)d_in[0];
    const float* pr = (const float*)d_in[1];   // reference uses pr_boxes[0] only

    float* pval = (float*)d_ws;                              // 512*16 floats
    int*   pidx = (int*)((char*)d_ws + 32 * 1024);           // 512*16 ints

    float* out_cls = (float*)d_out;                          // B*P*80
    float* out_loc = out_cls + (size_t)NBATCH * NPR * NC;    // B*P*4
    float* out_msk = out_loc + (size_t)NBATCH * NPR * 4;     // B*P

    dim3 g1(CHUNKS, NBATCH * NGT / GTPB);    // 16 x 64 = 1024 blocks
    k_bestp_part<<<g1, 256, 0, stream>>>(gt, pr, pval, pidx);

    dim3 g2(NPR / APB, NBATCH);              // 64 x 8 = 512 blocks
    k_assign<<<g2, 256, 0, stream>>>(gt, pr, pval, pidx, out_cls, out_loc, out_msk);
}